// Round 1
// baseline (453.634 us; speedup 1.0000x reference)
//
#include <hip/hip_runtime.h>
#include <stdint.h>

#define T_TOK 8192
#define H_DIM 1024
#define E_NUM 8
#define F_DIM 2048
#define BATCH 4
#define AUX_COEF 0.001f
#define Z_COEF 0.001f

#define NBLK_TOK 32       // blocks for hist/scatter (8192/256)

// ---- big-tile grouped GEMM params ----
#define GBM 256
#define GBN 256
#define GBK 32
#define MT_CAP 16         // 16*256 = 4096 rows capacity per expert (counts ~2048±55)

typedef __bf16 bf16x8 __attribute__((ext_vector_type(8)));
typedef float f32x4 __attribute__((ext_vector_type(4)));

__device__ __forceinline__ unsigned short f2bf(float f) {
    union { float f; uint32_t u; } v; v.f = f;
    uint32_t u = v.u;
    return (unsigned short)((u + 0x7FFFu + ((u >> 16) & 1u)) >> 16);
}
__device__ __forceinline__ float bf2f(unsigned short u) {
    union { uint32_t u; float f; } v; v.u = ((uint32_t)u) << 16; return v.f;
}

// async global->LDS, 16 B per lane; LDS dest = wave-uniform base + lane*16
__device__ __forceinline__ void gl_lds16(const void* g, void* l) {
    __builtin_amdgcn_global_load_lds((const __attribute__((address_space(1))) uint32_t*)g,
                                     (__attribute__((address_space(3))) uint32_t*)l, 16, 0, 0);
}

// ------------- transpose+convert: in [E,R,C] fp32 -> out [E,C,R] bf16 -------------
__global__ void transpose_conv_kernel(const float* __restrict__ in, unsigned short* __restrict__ out,
                                      int R, int C) {
    __shared__ float tile[32][33];
    int e = blockIdx.z;
    const float* ine = in + (size_t)e * R * C;
    unsigned short* oute = out + (size_t)e * R * C;
    int tx = threadIdx.x & 31, ty = threadIdx.x >> 5;  // 32x8
    int c0 = blockIdx.x * 32, r0 = blockIdx.y * 32;
#pragma unroll
    for (int i = 0; i < 4; i++) {
        int r = r0 + ty + i * 8;
        tile[ty + i * 8][tx] = ine[(size_t)r * C + c0 + tx];
    }
    __syncthreads();
#pragma unroll
    for (int i = 0; i < 4; i++) {
        int c = c0 + ty + i * 8;
        oute[(size_t)c * R + r0 + tx] = f2bf(tile[tx][ty + i * 8]);
    }
}

// ------- router (fused x->bf16 convert): logits, losses (block-partial), top-2 -------
__global__ void router_kernel(const float* __restrict__ x, const float* __restrict__ rw,
                              unsigned short* __restrict__ xb,
                              int* __restrict__ top2, float2* __restrict__ loss_part) {
    int wave = threadIdx.x >> 6;
    int lane = threadIdx.x & 63;
    int t = blockIdx.x * 4 + wave;
    const float4* xr = (const float4*)(x + (size_t)t * H_DIM);
    float4 xv[4];
#pragma unroll
    for (int k = 0; k < 4; k++) xv[k] = xr[lane + 64 * k];
    uint2* xo = (uint2*)(xb + (size_t)t * H_DIM);
#pragma unroll
    for (int k = 0; k < 4; k++) {
        uint2 o;
        o.x = (uint32_t)f2bf(xv[k].x) | ((uint32_t)f2bf(xv[k].y) << 16);
        o.y = (uint32_t)f2bf(xv[k].z) | ((uint32_t)f2bf(xv[k].w) << 16);
        xo[lane + 64 * k] = o;
    }
    float acc[E_NUM];
#pragma unroll
    for (int e = 0; e < E_NUM; e++) {
        const float4* rr = (const float4*)(rw + e * H_DIM);
        float s = 0.f;
#pragma unroll
        for (int k = 0; k < 4; k++) {
            float4 r = rr[lane + 64 * k];
            s += xv[k].x * r.x + xv[k].y * r.y + xv[k].z * r.z + xv[k].w * r.w;
        }
        acc[e] = s;
    }
#pragma unroll
    for (int e = 0; e < E_NUM; e++) {
        float v = acc[e];
#pragma unroll
        for (int off = 32; off; off >>= 1) v += __shfl_xor(v, off);
        acc[e] = v;
    }
    __shared__ float red[8];
    if (lane == 0) {
        float mx = acc[0];
#pragma unroll
        for (int e = 1; e < E_NUM; e++) mx = fmaxf(mx, acc[e]);
        float s = 0.f;
#pragma unroll
        for (int e = 0; e < E_NUM; e++) s += expf(acc[e] - mx);
        float lse = mx + logf(s);
        float slogp = 0.f, ssq = 0.f;
#pragma unroll
        for (int e = 0; e < E_NUM; e++) { slogp += acc[e] - lse; ssq += acc[e] * acc[e]; }
        int i1 = 0; float m1 = acc[0];
#pragma unroll
        for (int e = 1; e < E_NUM; e++) if (acc[e] > m1) { m1 = acc[e]; i1 = e; }
        int i2 = -1; float m2 = -1e30f;
#pragma unroll
        for (int e = 0; e < E_NUM; e++) if (e != i1 && acc[e] > m2) { m2 = acc[e]; i2 = e; }
        top2[t] = i1 | (i2 << 8);
        red[wave] = slogp;
        red[4 + wave] = ssq;
    }
    __syncthreads();
    if (threadIdx.x == 0) {
        float2 p;
        p.x = red[0] + red[1] + red[2] + red[3];
        p.y = red[4] + red[5] + red[6] + red[7];
        loss_part[blockIdx.x] = p;
    }
}

// ---------------- histogram: per-block expert counts (LDS bins) ----------------
__global__ void hist_kernel(const int* __restrict__ top2, int* __restrict__ blockcounts) {
    __shared__ int cnt[E_NUM];
    if (threadIdx.x < E_NUM) cnt[threadIdx.x] = 0;
    __syncthreads();
    int t = blockIdx.x * 256 + threadIdx.x;
    int v = top2[t];
    atomicAdd(&cnt[v & 255], 1);
    atomicAdd(&cnt[v >> 8], 1);
    __syncthreads();
    if (threadIdx.x < E_NUM) blockcounts[blockIdx.x * E_NUM + threadIdx.x] = cnt[threadIdx.x];
}

// ---------------- scan + loss finalize (1 block) ----------------
__global__ void scan_kernel(const int* __restrict__ blockcounts, const float2* __restrict__ loss_part,
                            int* __restrict__ counts, int* __restrict__ basep, int* __restrict__ offs,
                            float* __restrict__ loss_out) {
    __shared__ float redx[4], redy[4];
    int tid = threadIdx.x;
    float sx = 0.f, sy = 0.f;
    for (int i = tid; i < T_TOK / 4; i += 256) {
        float2 p = loss_part[i];
        sx += p.x; sy += p.y;
    }
#pragma unroll
    for (int off = 32; off; off >>= 1) { sx += __shfl_xor(sx, off); sy += __shfl_xor(sy, off); }
    if ((tid & 63) == 0) { redx[tid >> 6] = sx; redy[tid >> 6] = sy; }
    __syncthreads();
    if (tid == 0) {
        float slogp = redx[0] + redx[1] + redx[2] + redx[3];
        float ssq = redy[0] + redy[1] + redy[2] + redy[3];
        float ideal = 1.0f / E_NUM;
        float aux = ideal * ((float)T_TOK * E_NUM * logf(ideal) - slogp) / BATCH * AUX_COEF;
        float z = ssq / ((float)T_TOK * E_NUM) * Z_COEF;
        loss_out[0] = aux + z;
    }
    if (tid < E_NUM) {
        int s = 0;
        for (int b = 0; b < NBLK_TOK; b++) s += blockcounts[b * E_NUM + tid];
        counts[tid] = s;
    }
    __syncthreads();
    if (tid == 0) {
        int s = 0;
        for (int e = 0; e < E_NUM; e++) { basep[e] = s; s += counts[e]; }
    }
    __syncthreads();
    if (tid < E_NUM) {
        int o = basep[tid];
        for (int b = 0; b < NBLK_TOK; b++) { offs[b * E_NUM + tid] = o; o += blockcounts[b * E_NUM + tid]; }
    }
}

// -------- scatter: LDS cursors + per-block offsets; record each token's 2 positions --------
__global__ void scatter_kernel(const int* __restrict__ top2, const int* __restrict__ offs,
                               int* __restrict__ rowlist, int* __restrict__ posv) {
    __shared__ int cur[E_NUM];
    if (threadIdx.x < E_NUM) cur[threadIdx.x] = 0;
    __syncthreads();
    int t = blockIdx.x * 256 + threadIdx.x;
    int v = top2[t];
    int e0 = v & 255, e1 = v >> 8;
    int r0 = atomicAdd(&cur[e0], 1);
    int r1 = atomicAdd(&cur[e1], 1);
    int p0 = offs[blockIdx.x * E_NUM + e0] + r0;
    int p1 = offs[blockIdx.x * E_NUM + e1] + r1;
    rowlist[p0] = t;
    rowlist[p1] = t;
    posv[t] = p0 | (p1 << 16);
}

// ---- combine: out[t] = ybuf[p0] + ybuf[p1] + b2[e0] + b2[e1] ----
__global__ void combine_kernel(const int* __restrict__ top2, const int* __restrict__ posv,
                               const unsigned short* __restrict__ ybuf, const float* __restrict__ b2,
                               float* __restrict__ out) {
    int t = blockIdx.x;
    int v = top2[t];
    int p = posv[t];
    int e0 = v & 255, e1 = v >> 8;
    int p0 = p & 0xffff, p1 = (p >> 16) & 0xffff;
    int i = threadIdx.x;  // 256 threads x 4 elems
    const ushort4* y0 = (const ushort4*)(ybuf + (size_t)p0 * H_DIM);
    const ushort4* y1 = (const ushort4*)(ybuf + (size_t)p1 * H_DIM);
    const float4* q0 = (const float4*)(b2 + (size_t)e0 * H_DIM);
    const float4* q1 = (const float4*)(b2 + (size_t)e1 * H_DIM);
    ushort4 a = y0[i], b = y1[i];
    float4 c0 = q0[i], c1 = q1[i];
    float4 o;
    o.x = bf2f(a.x) + bf2f(b.x) + c0.x + c1.x;
    o.y = bf2f(a.y) + bf2f(b.y) + c0.y + c1.y;
    o.z = bf2f(a.z) + bf2f(b.z) + c0.z + c1.z;
    o.w = bf2f(a.w) + bf2f(b.w) + c0.w + c1.w;
    ((float4*)(out + (size_t)t * H_DIM))[i] = o;
}

// =====================================================================================
// Grouped GEMM, 256x256 tile, BK=32, 8 waves (2M x 4N), 4-slot LDS ring (4 x 32 KB),
// depth-3 prefetch with counted vmcnt (never drains to 0 in the main loop).
//
// LDS slot layout (32 KB): A tile 256 rows x 64 B at +0; B tile 256 rows x 64 B at +16384.
// Rows are 64 B => a b128 fragment read hits (mlane&1)*64 + quad*16 (mod 128): 8 lanes
// per 16B slot, all 32 banks evenly -> conflict-free floor, no XOR swizzle needed.
// gl_lds writes are linear (tid*16) => also even.
//
// Ring schedule (per K-tile t):
//   s_waitcnt vmcnt(8) lgkmcnt(0)   // in-order retire => tile t's 4 loads landed;
//   s_barrier                       //   lgkmcnt(0) drains our ds_reads of t-1 first
//   sched_barrier(0)
//   stage(t+3 -> slot (t+3)&3)      // slot (t-1)&3, freed by the barrier above
//   compute(t, slot t&3)            // 12 ds_read_b128 + 32 MFMA, setprio(1) wrapped
// Tail peeled with vmcnt(8)/vmcnt(4)/vmcnt(0).
// Block mapping: bid&7 = expert -> XCD; expert weight panel stays L2-resident per XCD.
// =====================================================================================
template<int KD, int NTILES_N, bool IS_G1>
__global__ __launch_bounds__(512, 2)
void gemm_big(const unsigned short* __restrict__ A,    // xb [T,H] (G1) or h1 [2T,F] (G2)
              const unsigned short* __restrict__ Bt,   // w1t [E,F,H] or w2t [E,H,F]  (B^T)
              const float* __restrict__ bias_p,        // b1 [E,F] (G1) or unused
              const int* __restrict__ rowlist,
              const int* __restrict__ basep,
              const int* __restrict__ counts,
              unsigned short* __restrict__ Out)        // h1 [2T,F] or ybuf [2T,H]
{
    constexpr int ND = NTILES_N * GBN;
    constexpr int NKT = KD / GBK;
    static_assert(NKT >= 4, "ring needs >=4 K-tiles");

    int bid = blockIdx.x;
    int e = bid & 7;
    int q = bid >> 3;
    int nt = q % NTILES_N;
    int mt = q / NTILES_N;
    int n_e = counts[e];
    if (mt * GBM >= n_e) return;
    int base_e = basep[e];

    __shared__ __attribute__((aligned(16))) unsigned char lds[4 * 32768];

    int tid = threadIdx.x;
    int wv = tid >> 6, lane = tid & 63;

    // ---- staging sources: per thread 2 A-rows + 2 B-rows, 16 B chunk each ----
    int srow = tid >> 2;       // 0..127
    int schunk = tid & 3;      // 16B chunk within the 64B (BK) row
    const unsigned short* aS[2];
    const unsigned short* bS[2];
#pragma unroll
    for (int c = 0; c < 2; c++) {
        int r = c * 128 + srow;
        if (IS_G1) {
            int ra = min(mt * GBM + r, n_e - 1);
            int tok = rowlist[base_e + ra];
            aS[c] = A + (size_t)tok * KD + schunk * 8;
        } else {
            int ra = base_e + min(mt * GBM + r, n_e - 1);
            aS[c] = A + (size_t)ra * KD + schunk * 8;
        }
        bS[c] = Bt + ((size_t)e * ND + nt * GBN + r) * KD + schunk * 8;
    }
    // wave-uniform LDS staging base (HW adds lane*16)
    char* ldsw = (char*)lds + wv * 1024;

    // ---- fragment read offsets within a slot ----
    int mlane = lane & 15, quad = lane >> 4;
    int wr = (wv >> 2) * 128;   // wave M base
    int wc = (wv & 3) * 64;     // wave N base
    int aOff[8], bOff[4];
#pragma unroll
    for (int mi = 0; mi < 8; mi++) aOff[mi] = (wr + mi * 16 + mlane) * 64 + quad * 16;
#pragma unroll
    for (int ni = 0; ni < 4; ni++) bOff[ni] = 16384 + (wc + ni * 16 + mlane) * 64 + quad * 16;

    f32x4 acc[8][4] = {};

    auto stage = [&](int t) {
        char* sb = ldsw + (size_t)(t & 3) * 32768;
        const unsigned short* a0 = aS[0] + t * GBK;
        const unsigned short* a1 = aS[1] + t * GBK;
        const unsigned short* b0 = bS[0] + t * GBK;
        const unsigned short* b1 = bS[1] + t * GBK;
        gl_lds16(a0, sb);
        gl_lds16(a1, sb + 8192);
        gl_lds16(b0, sb + 16384);
        gl_lds16(b1, sb + 24576);
    };
    auto compute = [&](int t) {
        char* sb = (char*)lds + (size_t)(t & 3) * 32768;
        __builtin_amdgcn_s_setprio(1);
        bf16x8 bfr[4];
#pragma unroll
        for (int ni = 0; ni < 4; ni++) bfr[ni] = *(const bf16x8*)(sb + bOff[ni]);
#pragma unroll
        for (int mi = 0; mi < 8; mi++) {
            bf16x8 af = *(const bf16x8*)(sb + aOff[mi]);
#pragma unroll
            for (int ni = 0; ni < 4; ni++)
                acc[mi][ni] = __builtin_amdgcn_mfma_f32_16x16x32_bf16(af, bfr[ni], acc[mi][ni], 0, 0, 0);
        }
        __builtin_amdgcn_s_setprio(0);
    };

    // prologue: fill 3 ring slots
    stage(0); stage(1); stage(2);

    for (int kt = 0; kt < NKT - 3; ++kt) {
        asm volatile("s_waitcnt vmcnt(8) lgkmcnt(0)" ::: "memory");
        __builtin_amdgcn_s_barrier();
        __builtin_amdgcn_sched_barrier(0);
        stage(kt + 3);
        compute(kt);
    }
    asm volatile("s_waitcnt vmcnt(8) lgkmcnt(0)" ::: "memory");
    __builtin_amdgcn_s_barrier();
    __builtin_amdgcn_sched_barrier(0);
    compute(NKT - 3);
    asm volatile("s_waitcnt vmcnt(4) lgkmcnt(0)" ::: "memory");
    __builtin_amdgcn_s_barrier();
    __builtin_amdgcn_sched_barrier(0);
    compute(NKT - 2);
    asm volatile("s_waitcnt vmcnt(0) lgkmcnt(0)" ::: "memory");
    __builtin_amdgcn_s_barrier();
    __builtin_amdgcn_sched_barrier(0);
    compute(NKT - 1);

    // ---- epilogue ----
    float bias[4];
#pragma unroll
    for (int ni = 0; ni < 4; ni++) {
        if (IS_G1) bias[ni] = bias_p[(size_t)e * ND + nt * GBN + wc + ni * 16 + mlane];
        else bias[ni] = 0.f;
    }
#pragma unroll
    for (int mi = 0; mi < 8; mi++) {
        int mbase = mt * GBM + wr + mi * 16 + quad * 4;
#pragma unroll
        for (int r = 0; r < 4; r++) {
            int m = mbase + r;
            if (m < n_e) {
                unsigned short* orow = Out + (size_t)(base_e + m) * ND + nt * GBN + wc + mlane;
#pragma unroll
                for (int ni = 0; ni < 4; ni++) {
                    float c = acc[mi][ni][r] + bias[ni];
                    if (IS_G1) c = c / (1.f + __expf(-c));
                    orow[ni * 16] = f2bf(c);
                }
            }
        }
    }
}

extern "C" void kernel_launch(void* const* d_in, const int* in_sizes, int n_in,
                              void* d_out, int out_size, void* d_ws, size_t ws_size,
                              hipStream_t stream) {
    const float* x = (const float*)d_in[0];
    const float* rw = (const float*)d_in[1];
    const float* w1 = (const float*)d_in[2];
    const float* b1 = (const float*)d_in[3];
    const float* w2 = (const float*)d_in[4];
    const float* b2 = (const float*)d_in[5];
    float* out = (float*)d_out;

    char* ws = (char*)d_ws;
    int* counts      = (int*)(ws + 0);          // 8 ints
    int* basep       = (int*)(ws + 64);         // 8 ints
    int* blockcounts = (int*)(ws + 128);        // 32*8 ints
    int* offs        = (int*)(ws + 2048);       // 32*8 ints
    float2* loss_part = (float2*)(ws + 4096);   // 2048 float2
    int* top2        = (int*)(ws + 32768);      // 8192 ints
    int* rowlist     = (int*)(ws + 65536);      // 16384 ints = 64 KB
    int* posv        = (int*)(ws + 131072);     // 8192 ints = 32 KB
    unsigned short* xb  = (unsigned short*)(ws + 163840);
    unsigned short* w1t = (unsigned short*)(ws + 163840 + 16777216ULL);
    unsigned short* w2t = (unsigned short*)(ws + 163840 + 16777216ULL + 33554432ULL);
    unsigned short* h1  = (unsigned short*)(ws + 163840 + 16777216ULL + 2ULL * 33554432ULL);
    unsigned short* ybuf = w1t;  // w1t (32 MB) is dead after gemm1; reuse for y [2T,H] bf16

    transpose_conv_kernel<<<dim3(64, 32, 8), 256, 0, stream>>>(w1, w1t, H_DIM, F_DIM);
    transpose_conv_kernel<<<dim3(32, 64, 8), 256, 0, stream>>>(w2, w2t, F_DIM, H_DIM);
    router_kernel<<<T_TOK / 4, 256, 0, stream>>>(x, rw, xb, top2, loss_part);
    hist_kernel<<<NBLK_TOK, 256, 0, stream>>>(top2, blockcounts);
    scan_kernel<<<1, 256, 0, stream>>>(blockcounts, loss_part, counts, basep, offs,
                                       out + (size_t)T_TOK * H_DIM);
    scatter_kernel<<<NBLK_TOK, 256, 0, stream>>>(top2, offs, rowlist, posv);
    // G1: K=H_DIM(1024), N=F_DIM => 8 n-tiles; grid = 8 experts * MT_CAP * 8
    gemm_big<H_DIM, F_DIM / GBN, true><<<8 * MT_CAP * (F_DIM / GBN), 512, 0, stream>>>(
        xb, w1t, b1, rowlist, basep, counts, h1);
    // G2: K=F_DIM(2048), N=H_DIM => 4 n-tiles; grid = 8 experts * MT_CAP * 4
    gemm_big<F_DIM, H_DIM / GBN, false><<<8 * MT_CAP * (H_DIM / GBN), 512, 0, stream>>>(
        h1, w2t, nullptr, rowlist, basep, counts, ybuf);
    combine_kernel<<<T_TOK, 256, 0, stream>>>(top2, posv, ybuf, b2, out);
}

// Round 3
// 449.472 us; speedup vs baseline: 1.0093x; 1.0093x over previous
//
#include <hip/hip_runtime.h>
#include <stdint.h>

#define T_TOK 8192
#define H_DIM 1024
#define E_NUM 8
#define F_DIM 2048
#define BATCH 4
#define AUX_COEF 0.001f
#define Z_COEF 0.001f

#define NBLK_TOK 32       // blocks for hist/scatter (8192/256)

// ---- big-tile grouped GEMM params ----
#define GBM 256
#define GBN 256
#define GBK 64
#define MT_CAP 16         // 16*256 = 4096 rows capacity per expert (counts ~2048±55)

typedef __bf16 bf16x8 __attribute__((ext_vector_type(8)));
typedef float f32x4 __attribute__((ext_vector_type(4)));

__device__ __forceinline__ unsigned short f2bf(float f) {
    union { float f; uint32_t u; } v; v.f = f;
    uint32_t u = v.u;
    return (unsigned short)((u + 0x7FFFu + ((u >> 16) & 1u)) >> 16);
}
__device__ __forceinline__ float bf2f(unsigned short u) {
    union { uint32_t u; float f; } v; v.u = ((uint32_t)u) << 16; return v.f;
}

// async global->LDS, 16 B per lane; LDS dest = wave-uniform base + lane*16
__device__ __forceinline__ void gl_lds16(const void* g, void* l) {
    __builtin_amdgcn_global_load_lds((const __attribute__((address_space(1))) uint32_t*)g,
                                     (__attribute__((address_space(3))) uint32_t*)l, 16, 0, 0);
}

// ------------- transpose+convert: in [E,R,C] fp32 -> out [E,C,R] bf16 -------------
__global__ void transpose_conv_kernel(const float* __restrict__ in, unsigned short* __restrict__ out,
                                      int R, int C) {
    __shared__ float tile[32][33];
    int e = blockIdx.z;
    const float* ine = in + (size_t)e * R * C;
    unsigned short* oute = out + (size_t)e * R * C;
    int tx = threadIdx.x & 31, ty = threadIdx.x >> 5;  // 32x8
    int c0 = blockIdx.x * 32, r0 = blockIdx.y * 32;
#pragma unroll
    for (int i = 0; i < 4; i++) {
        int r = r0 + ty + i * 8;
        tile[ty + i * 8][tx] = ine[(size_t)r * C + c0 + tx];
    }
    __syncthreads();
#pragma unroll
    for (int i = 0; i < 4; i++) {
        int c = c0 + ty + i * 8;
        oute[(size_t)c * R + r0 + tx] = f2bf(tile[tx][ty + i * 8]);
    }
}

// ------- router (fused x->bf16 convert): logits, losses (block-partial), top-2 -------
__global__ void router_kernel(const float* __restrict__ x, const float* __restrict__ rw,
                              unsigned short* __restrict__ xb,
                              int* __restrict__ top2, float2* __restrict__ loss_part) {
    int wave = threadIdx.x >> 6;
    int lane = threadIdx.x & 63;
    int t = blockIdx.x * 4 + wave;
    const float4* xr = (const float4*)(x + (size_t)t * H_DIM);
    float4 xv[4];
#pragma unroll
    for (int k = 0; k < 4; k++) xv[k] = xr[lane + 64 * k];
    uint2* xo = (uint2*)(xb + (size_t)t * H_DIM);
#pragma unroll
    for (int k = 0; k < 4; k++) {
        uint2 o;
        o.x = (uint32_t)f2bf(xv[k].x) | ((uint32_t)f2bf(xv[k].y) << 16);
        o.y = (uint32_t)f2bf(xv[k].z) | ((uint32_t)f2bf(xv[k].w) << 16);
        xo[lane + 64 * k] = o;
    }
    float acc[E_NUM];
#pragma unroll
    for (int e = 0; e < E_NUM; e++) {
        const float4* rr = (const float4*)(rw + e * H_DIM);
        float s = 0.f;
#pragma unroll
        for (int k = 0; k < 4; k++) {
            float4 r = rr[lane + 64 * k];
            s += xv[k].x * r.x + xv[k].y * r.y + xv[k].z * r.z + xv[k].w * r.w;
        }
        acc[e] = s;
    }
#pragma unroll
    for (int e = 0; e < E_NUM; e++) {
        float v = acc[e];
#pragma unroll
        for (int off = 32; off; off >>= 1) v += __shfl_xor(v, off);
        acc[e] = v;
    }
    __shared__ float red[8];
    if (lane == 0) {
        float mx = acc[0];
#pragma unroll
        for (int e = 1; e < E_NUM; e++) mx = fmaxf(mx, acc[e]);
        float s = 0.f;
#pragma unroll
        for (int e = 0; e < E_NUM; e++) s += expf(acc[e] - mx);
        float lse = mx + logf(s);
        float slogp = 0.f, ssq = 0.f;
#pragma unroll
        for (int e = 0; e < E_NUM; e++) { slogp += acc[e] - lse; ssq += acc[e] * acc[e]; }
        int i1 = 0; float m1 = acc[0];
#pragma unroll
        for (int e = 1; e < E_NUM; e++) if (acc[e] > m1) { m1 = acc[e]; i1 = e; }
        int i2 = -1; float m2 = -1e30f;
#pragma unroll
        for (int e = 0; e < E_NUM; e++) if (e != i1 && acc[e] > m2) { m2 = acc[e]; i2 = e; }
        top2[t] = i1 | (i2 << 8);
        red[wave] = slogp;
        red[4 + wave] = ssq;
    }
    __syncthreads();
    if (threadIdx.x == 0) {
        float2 p;
        p.x = red[0] + red[1] + red[2] + red[3];
        p.y = red[4] + red[5] + red[6] + red[7];
        loss_part[blockIdx.x] = p;
    }
}

// ---------------- histogram: per-block expert counts (LDS bins) ----------------
__global__ void hist_kernel(const int* __restrict__ top2, int* __restrict__ blockcounts) {
    __shared__ int cnt[E_NUM];
    if (threadIdx.x < E_NUM) cnt[threadIdx.x] = 0;
    __syncthreads();
    int t = blockIdx.x * 256 + threadIdx.x;
    int v = top2[t];
    atomicAdd(&cnt[v & 255], 1);
    atomicAdd(&cnt[v >> 8], 1);
    __syncthreads();
    if (threadIdx.x < E_NUM) blockcounts[blockIdx.x * E_NUM + threadIdx.x] = cnt[threadIdx.x];
}

// ---------------- scan + loss finalize (1 block) ----------------
__global__ void scan_kernel(const int* __restrict__ blockcounts, const float2* __restrict__ loss_part,
                            int* __restrict__ counts, int* __restrict__ basep, int* __restrict__ offs,
                            float* __restrict__ loss_out) {
    __shared__ float redx[4], redy[4];
    int tid = threadIdx.x;
    float sx = 0.f, sy = 0.f;
    for (int i = tid; i < T_TOK / 4; i += 256) {
        float2 p = loss_part[i];
        sx += p.x; sy += p.y;
    }
#pragma unroll
    for (int off = 32; off; off >>= 1) { sx += __shfl_xor(sx, off); sy += __shfl_xor(sy, off); }
    if ((tid & 63) == 0) { redx[tid >> 6] = sx; redy[tid >> 6] = sy; }
    __syncthreads();
    if (tid == 0) {
        float slogp = redx[0] + redx[1] + redx[2] + redx[3];
        float ssq = redy[0] + redy[1] + redy[2] + redy[3];
        float ideal = 1.0f / E_NUM;
        float aux = ideal * ((float)T_TOK * E_NUM * logf(ideal) - slogp) / BATCH * AUX_COEF;
        float z = ssq / ((float)T_TOK * E_NUM) * Z_COEF;
        loss_out[0] = aux + z;
    }
    if (tid < E_NUM) {
        int s = 0;
        for (int b = 0; b < NBLK_TOK; b++) s += blockcounts[b * E_NUM + tid];
        counts[tid] = s;
    }
    __syncthreads();
    if (tid == 0) {
        int s = 0;
        for (int e = 0; e < E_NUM; e++) { basep[e] = s; s += counts[e]; }
    }
    __syncthreads();
    if (tid < E_NUM) {
        int o = basep[tid];
        for (int b = 0; b < NBLK_TOK; b++) { offs[b * E_NUM + tid] = o; o += blockcounts[b * E_NUM + tid]; }
    }
}

// -------- scatter: LDS cursors + per-block offsets; record each token's 2 positions --------
__global__ void scatter_kernel(const int* __restrict__ top2, const int* __restrict__ offs,
                               int* __restrict__ rowlist, int* __restrict__ posv) {
    __shared__ int cur[E_NUM];
    if (threadIdx.x < E_NUM) cur[threadIdx.x] = 0;
    __syncthreads();
    int t = blockIdx.x * 256 + threadIdx.x;
    int v = top2[t];
    int e0 = v & 255, e1 = v >> 8;
    int r0 = atomicAdd(&cur[e0], 1);
    int r1 = atomicAdd(&cur[e1], 1);
    int p0 = offs[blockIdx.x * E_NUM + e0] + r0;
    int p1 = offs[blockIdx.x * E_NUM + e1] + r1;
    rowlist[p0] = t;
    rowlist[p1] = t;
    posv[t] = p0 | (p1 << 16);
}

// ---- combine: out[t] = ybuf[p0] + ybuf[p1] + b2[e0] + b2[e1] ----
__global__ void combine_kernel(const int* __restrict__ top2, const int* __restrict__ posv,
                               const unsigned short* __restrict__ ybuf, const float* __restrict__ b2,
                               float* __restrict__ out) {
    int t = blockIdx.x;
    int v = top2[t];
    int p = posv[t];
    int e0 = v & 255, e1 = v >> 8;
    int p0 = p & 0xffff, p1 = (p >> 16) & 0xffff;
    int i = threadIdx.x;  // 256 threads x 4 elems
    const ushort4* y0 = (const ushort4*)(ybuf + (size_t)p0 * H_DIM);
    const ushort4* y1 = (const ushort4*)(ybuf + (size_t)p1 * H_DIM);
    const float4* q0 = (const float4*)(b2 + (size_t)e0 * H_DIM);
    const float4* q1 = (const float4*)(b2 + (size_t)e1 * H_DIM);
    ushort4 a = y0[i], b = y1[i];
    float4 c0 = q0[i], c1 = q1[i];
    float4 o;
    o.x = bf2f(a.x) + bf2f(b.x) + c0.x + c1.x;
    o.y = bf2f(a.y) + bf2f(b.y) + c0.y + c1.y;
    o.z = bf2f(a.z) + bf2f(b.z) + c0.z + c1.z;
    o.w = bf2f(a.w) + bf2f(b.w) + c0.w + c1.w;
    ((float4*)(out + (size_t)t * H_DIM))[i] = o;
}

// =====================================================================================
// Grouped GEMM, 256x256 tile, BK=64, 8 waves (2M x 4N), 8-phase schedule (m201 port).
//
// LDS: 2 buffers x (A 32KB + B 32KB) = 128 KB. Row = 128 B = 8 chunks of 16 B;
// chunk swizzle: LDS[r][c] holds global chunk c^(r&7) (round-0 verified: 0 conflicts).
// Stager: thread tid stages row srow=tid>>3 (+64*i), fetching global chunk
// (tid&7)^(srow&7); LDS dest linear (wave-uniform + lane*16).
// Reader: byte = r*128 + ((ks*64 + quad*16) ^ ((mlane&7)<<4)).
//
// Per K-tile t: 4 phases, each {ds-read quadrant frags; stage 1 half-tile; s_barrier;
// lgkmcnt(0); sched_barrier; setprio(1); 16 MFMA; setprio(0); s_barrier}.
//   ph1: read A[0:4]+B[0:2] (12), stage B-h1(t+1), MFMA Q00
//   ph2: read B[2:4]       (4),  stage A-h1(t+1), MFMA Q01
//   ph3: read A[4:8]       (8),  stage B-h0(t+2), MFMA Q10
//   ph4: (0 reads),              stage A-h0(t+2), MFMA Q11, vmcnt(4)+barrier
// Race-freedom: a region's reads drain (lgkmcnt(0)) at least one barrier before its
// overwrite is issued. Tile t+1 fully staged by ph2 => vmcnt(4) at tile boundary
// (only ph3/ph4's 4 loads may be outstanding); vmcnt(0) in the tail.
// Block mapping: bid&7 = expert -> XCD; expert weight panel stays L2-resident per XCD.
// =====================================================================================
template<int KD, int NTILES_N, bool IS_G1>
__global__ __launch_bounds__(512, 2)
void gemm8p(const unsigned short* __restrict__ A,    // xb [T,H] (G1) or h1 [2T,F] (G2)
            const unsigned short* __restrict__ Bt,   // w1t [E,F,H] or w2t [E,H,F]  (B^T)
            const float* __restrict__ bias_p,        // b1 [E,F] (G1) or unused
            const int* __restrict__ rowlist,
            const int* __restrict__ basep,
            const int* __restrict__ counts,
            unsigned short* __restrict__ Out)        // h1 [2T,F] or ybuf [2T,H]
{
    constexpr int ND = NTILES_N * GBN;
    constexpr int NKT = KD / GBK;
    static_assert(NKT >= 4, "pipeline needs >=4 K-tiles");

    int bid = blockIdx.x;
    int e = bid & 7;
    int q = bid >> 3;
    int nt = q % NTILES_N;
    int mt = q / NTILES_N;
    int n_e = counts[e];
    if (mt * GBM >= n_e) return;
    int base_e = basep[e];

    __shared__ __attribute__((aligned(16))) unsigned char lds[2][65536];

    int tid = threadIdx.x;
    int wv = tid >> 6, lane = tid & 63;

    // ---- staging sources: thread stages rows srow+{0,64,128,192}, swizzled chunk gc ----
    int srow = tid >> 3;                       // 0..63
    int gc = (tid & 7) ^ (srow & 7);           // global 16B chunk this thread fetches
    const unsigned short* aS[4];
    const unsigned short* bS[4];
#pragma unroll
    for (int i = 0; i < 4; i++) {
        int r = srow + i * 64;
        size_t ra;
        if (IS_G1) {
            int rr = min(mt * GBM + r, n_e - 1);
            ra = (size_t)rowlist[base_e + rr];
        } else {
            ra = (size_t)(base_e + min(mt * GBM + r, n_e - 1));
        }
        aS[i] = A + ra * KD + gc * 8;
        bS[i] = Bt + ((size_t)e * ND + nt * GBN + r) * KD + gc * 8;
    }

    auto stageA = [&](int buf, int h, int t) {   // A half h (rows h*128..h*128+127) of K-tile t
        char* d = (char*)lds + buf * 65536 + h * 16384 + wv * 1024;
        gl_lds16(aS[h * 2 + 0] + t * GBK, d);
        gl_lds16(aS[h * 2 + 1] + t * GBK, d + 8192);
    };
    auto stageB = [&](int buf, int h, int t) {
        char* d = (char*)lds + buf * 65536 + 32768 + h * 16384 + wv * 1024;
        gl_lds16(bS[h * 2 + 0] + t * GBK, d);
        gl_lds16(bS[h * 2 + 1] + t * GBK, d + 8192);
    };

    // ---- reader geometry ----
    int mlane = lane & 15, quad = lane >> 4;
    int wr = (wv >> 2) * 128;   // wave M base
    int wc = (wv & 3) * 64;     // wave N base
    int xk0 = (quad * 16) ^ ((mlane & 7) << 4);
    int xk1 = (64 + quad * 16) ^ ((mlane & 7) << 4);
    int aRow = (wr + mlane) * 128;            // + mi*2048 + xk[ks]
    int bRow = 32768 + (wc + mlane) * 128;    // + ni*2048 + xk[ks]

    f32x4 acc[8][4] = {};
    bf16x8 a03[4][2], a47[4][2], b01[2][2], b23[2][2];

    // ---- prologue: tile0 fully + tile1's B-h0, A-h0 ----
    stageA(0, 0, 0); stageA(0, 1, 0); stageB(0, 0, 0); stageB(0, 1, 0);
    if (NKT > 1) { stageB(1, 0, 1); stageA(1, 0, 1); }
    asm volatile("s_waitcnt vmcnt(4)" ::: "memory");
    __builtin_amdgcn_s_barrier();

    for (int t = 0; t < NKT; ++t) {
        const char* Ab = (const char*)lds + (t & 1) * 65536;
        int nb = (t + 1) & 1;

        // ---- phase 1: A[0:4], B[0:2]; stage B-h1(t+1); MFMA Q00 ----
#pragma unroll
        for (int mi = 0; mi < 4; mi++) {
            a03[mi][0] = *(const bf16x8*)(Ab + aRow + mi * 2048 + xk0);
            a03[mi][1] = *(const bf16x8*)(Ab + aRow + mi * 2048 + xk1);
        }
#pragma unroll
        for (int ni = 0; ni < 2; ni++) {
            b01[ni][0] = *(const bf16x8*)(Ab + bRow + ni * 2048 + xk0);
            b01[ni][1] = *(const bf16x8*)(Ab + bRow + ni * 2048 + xk1);
        }
        if (t + 1 < NKT) stageB(nb, 1, t + 1);
        __builtin_amdgcn_s_barrier();
        asm volatile("s_waitcnt lgkmcnt(0)" ::: "memory");
        __builtin_amdgcn_sched_barrier(0);
        __builtin_amdgcn_s_setprio(1);
#pragma unroll
        for (int ks = 0; ks < 2; ks++)
#pragma unroll
            for (int mi = 0; mi < 4; mi++)
#pragma unroll
                for (int ni = 0; ni < 2; ni++)
                    acc[mi][ni] = __builtin_amdgcn_mfma_f32_16x16x32_bf16(a03[mi][ks], b01[ni][ks], acc[mi][ni], 0, 0, 0);
        __builtin_amdgcn_s_setprio(0);
        __builtin_amdgcn_s_barrier();

        // ---- phase 2: B[2:4]; stage A-h1(t+1); MFMA Q01 ----
#pragma unroll
        for (int ni = 0; ni < 2; ni++) {
            b23[ni][0] = *(const bf16x8*)(Ab + bRow + (ni + 2) * 2048 + xk0);
            b23[ni][1] = *(const bf16x8*)(Ab + bRow + (ni + 2) * 2048 + xk1);
        }
        if (t + 1 < NKT) stageA(nb, 1, t + 1);
        __builtin_amdgcn_s_barrier();
        asm volatile("s_waitcnt lgkmcnt(0)" ::: "memory");
        __builtin_amdgcn_sched_barrier(0);
        __builtin_amdgcn_s_setprio(1);
#pragma unroll
        for (int ks = 0; ks < 2; ks++)
#pragma unroll
            for (int mi = 0; mi < 4; mi++)
#pragma unroll
                for (int ni = 0; ni < 2; ni++)
                    acc[mi][ni + 2] = __builtin_amdgcn_mfma_f32_16x16x32_bf16(a03[mi][ks], b23[ni][ks], acc[mi][ni + 2], 0, 0, 0);
        __builtin_amdgcn_s_setprio(0);
        __builtin_amdgcn_s_barrier();

        // ---- phase 3: A[4:8]; stage B-h0(t+2); MFMA Q10 ----
#pragma unroll
        for (int mi = 0; mi < 4; mi++) {
            a47[mi][0] = *(const bf16x8*)(Ab + aRow + (mi + 4) * 2048 + xk0);
            a47[mi][1] = *(const bf16x8*)(Ab + aRow + (mi + 4) * 2048 + xk1);
        }
        if (t + 2 < NKT) stageB(t & 1, 0, t + 2);
        __builtin_amdgcn_s_barrier();
        asm volatile("s_waitcnt lgkmcnt(0)" ::: "memory");
        __builtin_amdgcn_sched_barrier(0);
        __builtin_amdgcn_s_setprio(1);
#pragma unroll
        for (int ks = 0; ks < 2; ks++)
#pragma unroll
            for (int mi = 0; mi < 4; mi++)
#pragma unroll
                for (int ni = 0; ni < 2; ni++)
                    acc[mi + 4][ni] = __builtin_amdgcn_mfma_f32_16x16x32_bf16(a47[mi][ks], b01[ni][ks], acc[mi + 4][ni], 0, 0, 0);
        __builtin_amdgcn_s_setprio(0);
        __builtin_amdgcn_s_barrier();

        // ---- phase 4: stage A-h0(t+2); MFMA Q11; tile-boundary vmcnt ----
        if (t + 2 < NKT) stageA(t & 1, 0, t + 2);
        __builtin_amdgcn_s_barrier();
        __builtin_amdgcn_sched_barrier(0);
        __builtin_amdgcn_s_setprio(1);
#pragma unroll
        for (int ks = 0; ks < 2; ks++)
#pragma unroll
            for (int mi = 0; mi < 4; mi++)
#pragma unroll
                for (int ni = 0; ni < 2; ni++)
                    acc[mi + 4][ni + 2] = __builtin_amdgcn_mfma_f32_16x16x32_bf16(a47[mi][ks], b23[ni][ks], acc[mi + 4][ni + 2], 0, 0, 0);
        __builtin_amdgcn_s_setprio(0);
        if (t + 2 < NKT) {
            asm volatile("s_waitcnt vmcnt(4)" ::: "memory");   // ph3/ph4 stages may stay in flight
        } else {
            asm volatile("s_waitcnt vmcnt(0)" ::: "memory");   // tail: drain
        }
        __builtin_amdgcn_s_barrier();
    }

    // ---- epilogue ----
    float bias[4];
#pragma unroll
    for (int ni = 0; ni < 4; ni++) {
        if (IS_G1) bias[ni] = bias_p[(size_t)e * ND + nt * GBN + wc + ni * 16 + mlane];
        else bias[ni] = 0.f;
    }
#pragma unroll
    for (int mi = 0; mi < 8; mi++) {
        int mbase = mt * GBM + wr + mi * 16 + quad * 4;
#pragma unroll
        for (int r = 0; r < 4; r++) {
            int m = mbase + r;
            if (m < n_e) {
                unsigned short* orow = Out + (size_t)(base_e + m) * ND + nt * GBN + wc + mlane;
#pragma unroll
                for (int ni = 0; ni < 4; ni++) {
                    float c = acc[mi][ni][r] + bias[ni];
                    if (IS_G1) c = c / (1.f + __expf(-c));
                    orow[ni * 16] = f2bf(c);
                }
            }
        }
    }
}

extern "C" void kernel_launch(void* const* d_in, const int* in_sizes, int n_in,
                              void* d_out, int out_size, void* d_ws, size_t ws_size,
                              hipStream_t stream) {
    const float* x = (const float*)d_in[0];
    const float* rw = (const float*)d_in[1];
    const float* w1 = (const float*)d_in[2];
    const float* b1 = (const float*)d_in[3];
    const float* w2 = (const float*)d_in[4];
    const float* b2 = (const float*)d_in[5];
    float* out = (float*)d_out;

    char* ws = (char*)d_ws;
    int* counts      = (int*)(ws + 0);          // 8 ints
    int* basep       = (int*)(ws + 64);         // 8 ints
    int* blockcounts = (int*)(ws + 128);        // 32*8 ints
    int* offs        = (int*)(ws + 2048);       // 32*8 ints
    float2* loss_part = (float2*)(ws + 4096);   // 2048 float2
    int* top2        = (int*)(ws + 32768);      // 8192 ints
    int* rowlist     = (int*)(ws + 65536);      // 16384 ints = 64 KB
    int* posv        = (int*)(ws + 131072);     // 8192 ints = 32 KB
    unsigned short* xb  = (unsigned short*)(ws + 163840);
    unsigned short* w1t = (unsigned short*)(ws + 163840 + 16777216ULL);
    unsigned short* w2t = (unsigned short*)(ws + 163840 + 16777216ULL + 33554432ULL);
    unsigned short* h1  = (unsigned short*)(ws + 163840 + 16777216ULL + 2ULL * 33554432ULL);
    unsigned short* ybuf = w1t;  // w1t (32 MB) is dead after gemm1; reuse for y [2T,H] bf16

    transpose_conv_kernel<<<dim3(64, 32, 8), 256, 0, stream>>>(w1, w1t, H_DIM, F_DIM);
    transpose_conv_kernel<<<dim3(32, 64, 8), 256, 0, stream>>>(w2, w2t, F_DIM, H_DIM);
    router_kernel<<<T_TOK / 4, 256, 0, stream>>>(x, rw, xb, top2, loss_part);
    hist_kernel<<<NBLK_TOK, 256, 0, stream>>>(top2, blockcounts);
    scan_kernel<<<1, 256, 0, stream>>>(blockcounts, loss_part, counts, basep, offs,
                                       out + (size_t)T_TOK * H_DIM);
    scatter_kernel<<<NBLK_TOK, 256, 0, stream>>>(top2, offs, rowlist, posv);
    // G1: K=H_DIM(1024) -> NKT=16; N=F_DIM => 8 n-tiles
    gemm8p<H_DIM, F_DIM / GBN, true><<<8 * MT_CAP * (F_DIM / GBN), 512, 0, stream>>>(
        xb, w1t, b1, rowlist, basep, counts, h1);
    // G2: K=F_DIM(2048) -> NKT=32; N=H_DIM => 4 n-tiles
    gemm8p<F_DIM, H_DIM / GBN, false><<<8 * MT_CAP * (H_DIM / GBN), 512, 0, stream>>>(
        h1, w2t, nullptr, rowlist, basep, counts, ybuf);
    combine_kernel<<<T_TOK, 256, 0, stream>>>(top2, posv, ybuf, b2, out);
}